// Round 15
// baseline (1260.007 us; speedup 1.0000x reference)
//
#include <hip/hip_runtime.h>
#include <stdint.h>

typedef short bf16x8 __attribute__((ext_vector_type(8)));
typedef float f32x4 __attribute__((ext_vector_type(4)));
typedef unsigned int u32x4 __attribute__((ext_vector_type(4)));

__device__ __forceinline__ unsigned short f2bf(float f) {
  union { float f; unsigned int i; } v; v.f = f;
  unsigned int r = v.i + 0x7FFF + ((v.i >> 16) & 1);
  return (unsigned short)(r >> 16);
}
__device__ __forceinline__ float bfu2f(unsigned short u) {
  union { unsigned int i; float f; } v; v.i = ((unsigned int)u) << 16; return v.f;
}
__device__ __forceinline__ void gload_lds16(const void* g, void* l) {
  __builtin_amdgcn_global_load_lds(
      (const __attribute__((address_space(1))) unsigned int*)g,
      (__attribute__((address_space(3))) unsigned int*)l,
      16, 0, 0);
}
// coherent (IC-level) 16B store: single instruction => tag+data commit atomically
__device__ __forceinline__ void store16_coh(unsigned int* p, u32x4 v) {
  asm volatile("global_store_dwordx4 %0, %1, off sc0 sc1" :: "v"(p), "v"(v) : "memory");
}
__device__ __forceinline__ void spin_load6(const unsigned int* p0, const unsigned int* p1,
                                           const unsigned int* p2, const unsigned int* p3,
                                           const unsigned int* p4, const unsigned int* p5,
                                           u32x4& r0, u32x4& r1, u32x4& r2,
                                           u32x4& r3, u32x4& r4, u32x4& r5) {
  asm volatile(
      "global_load_dwordx4 %0, %6, off sc0 sc1\n\t"
      "global_load_dwordx4 %1, %7, off sc0 sc1\n\t"
      "global_load_dwordx4 %2, %8, off sc0 sc1\n\t"
      "global_load_dwordx4 %3, %9, off sc0 sc1\n\t"
      "global_load_dwordx4 %4, %10, off sc0 sc1\n\t"
      "global_load_dwordx4 %5, %11, off sc0 sc1\n\t"
      "s_waitcnt vmcnt(0)"
      : "=&v"(r0), "=&v"(r1), "=&v"(r2), "=&v"(r3), "=&v"(r4), "=&v"(r5)
      : "v"(p0), "v"(p1), "v"(p2), "v"(p3), "v"(p4), "v"(p5)
      : "memory");
}
__device__ __forceinline__ void spin_load3p(const unsigned int* p0, const unsigned int* p1,
                                            const unsigned int* p2, const unsigned int* pp,
                                            u32x4& r0, u32x4& r1, u32x4& r2, unsigned int& pt) {
  asm volatile(
      "global_load_dwordx4 %0, %4, off sc0 sc1\n\t"
      "global_load_dwordx4 %1, %5, off sc0 sc1\n\t"
      "global_load_dwordx4 %2, %6, off sc0 sc1\n\t"
      "global_load_dword %3, %7, off sc0 sc1\n\t"
      "s_waitcnt vmcnt(0)"
      : "=&v"(r0), "=&v"(r1), "=&v"(r2), "=&v"(pt)
      : "v"(p0), "v"(p1), "v"(p2), "v"(pp)
      : "memory");
}

// ------------- convert f32 weights -> bf16 (Whh0, Wih1, Whh1, Wout, Wdec) -------------
__global__ __launch_bounds__(256) void k_cvt(const float* __restrict__ s0, const float* __restrict__ s1,
                                             const float* __restrict__ s2, const float* __restrict__ s3,
                                             const float* __restrict__ s4,
                                             unsigned short* __restrict__ d0, unsigned short* __restrict__ d1,
                                             unsigned short* __restrict__ d2, unsigned short* __restrict__ d3,
                                             unsigned short* __restrict__ d4) {
  int j = blockIdx.x * 256 + threadIdx.x;   // 6912*256 = 1,769,472 vec8 jobs exactly
  const float* s; unsigned short* d; int o;
  if (j < 524288)       { s = s0; d = d0; o = j; }
  else if (j < 1048576) { s = s1; d = d1; o = j - 524288; }
  else if (j < 1572864) { s = s2; d = d2; o = j - 1048576; }
  else if (j < 1703936) { s = s3; d = d3; o = j - 1572864; }
  else                  { s = s4; d = d4; o = j - 1703936; }
  size_t off = (size_t)o * 8;
  f32x4 v0 = *(const f32x4*)(s + off);
  f32x4 v1 = *(const f32x4*)(s + off + 4);
  bf16x8 r;
#pragma unroll
  for (int k = 0; k < 4; k++) { r[k] = (short)f2bf(v0[k]); r[4 + k] = (short)f2bf(v1[k]); }
  *(bf16x8*)(d + off) = r;
}

// ---------------- prep: embedding gather (f32) + zero exchange + dtag ----------------
__global__ __launch_bounds__(256) void k_prep(const int* __restrict__ ys,
                                              const float* __restrict__ embed,
                                              float* __restrict__ eys,
                                              unsigned int* __restrict__ exch,
                                              unsigned int* __restrict__ dtag) {
  int idx = blockIdx.x * 256 + threadIdx.x;   // 16384 threads
  int row = idx >> 6;
  int e = (idx & 63) * 8;
  int y = ys[row];
  f32x4 v0 = {0.f, 0.f, 0.f, 0.f}, v1 = {0.f, 0.f, 0.f, 0.f};
  if (y != 0) {
    v0 = *(const f32x4*)(embed + (size_t)y * 512 + e);
    v1 = *(const f32x4*)(embed + (size_t)y * 512 + e + 4);
  }
  *(f32x4*)(eys + (size_t)row * 512 + e) = v0;
  *(f32x4*)(eys + (size_t)row * 512 + e + 4) = v1;
  exch[idx] = 0u;                 // 32768 dwords: h0[2][8192] + h1[2][8192]
  exch[idx + 16384] = 0u;
  if (idx < 1024) dtag[idx] = 0u;
}

// -------- generic small GEMM: C = A(f32 MxK) @ W(f32 NxK)^T + b1 + b2; C f32 or bf16 ----
__global__ __launch_bounds__(256) void k_gemm_bias(const float* __restrict__ A,
                                                   const float* __restrict__ W,
                                                   const float* __restrict__ b1,
                                                   const float* __restrict__ b2,
                                                   void* __restrict__ Cout, int obf,
                                                   int M, int N, int K) {
  __shared__ unsigned short Als[64][40];
  __shared__ unsigned short Wls[64][40];
  int tid = threadIdx.x;
  int lane = tid & 63, wid = tid >> 6;
  int mtiles = M >> 6;
  int mt = blockIdx.x % mtiles, nt = blockIdx.x / mtiles;
  int srow = tid >> 2, sseg = tid & 3;
  f32x4 acc[4];
#pragma unroll
  for (int nf = 0; nf < 4; nf++) acc[nf] = (f32x4){0.f, 0.f, 0.f, 0.f};

  for (int kc = 0; kc < K; kc += 32) {
    const float* ap = A + (size_t)(mt * 64 + srow) * K + kc + sseg * 8;
    const float* wp = W + (size_t)(nt * 64 + srow) * K + kc + sseg * 8;
    f32x4 a0 = *(const f32x4*)ap, a1 = *(const f32x4*)(ap + 4);
    f32x4 w0 = *(const f32x4*)wp, w1 = *(const f32x4*)(wp + 4);
    bf16x8 av, wv;
#pragma unroll
    for (int k = 0; k < 4; k++) {
      av[k] = (short)f2bf(a0[k]); av[4 + k] = (short)f2bf(a1[k]);
      wv[k] = (short)f2bf(w0[k]); wv[4 + k] = (short)f2bf(w1[k]);
    }
    __syncthreads();
    *(bf16x8*)(&Als[srow][sseg * 8]) = av;
    *(bf16x8*)(&Wls[srow][sseg * 8]) = wv;
    __syncthreads();
    bf16x8 af = *(const bf16x8*)(&Als[wid * 16 + (lane & 15)][(lane >> 4) * 8]);
#pragma unroll
    for (int nf = 0; nf < 4; nf++) {
      bf16x8 bf = *(const bf16x8*)(&Wls[nf * 16 + (lane & 15)][(lane >> 4) * 8]);
      acc[nf] = __builtin_amdgcn_mfma_f32_16x16x32_bf16(af, bf, acc[nf], 0, 0, 0);
    }
  }
  int rloc = (lane >> 4) * 4;
  int col0 = lane & 15;
#pragma unroll
  for (int nf = 0; nf < 4; nf++) {
    int n = nt * 64 + nf * 16 + col0;
    float bias = 0.f;
    if (b1) bias += b1[n];
    if (b2) bias += b2[n];
#pragma unroll
    for (int r = 0; r < 4; r++) {
      int m = mt * 64 + wid * 16 + rloc + r;
      float v = acc[nf][r] + bias;
      if (obf) ((unsigned short*)Cout)[(size_t)m * N + n] = f2bf(v);
      else     ((float*)Cout)[(size_t)m * N + n] = v;
    }
  }
}

// ================= MEGA KERNEL: LSTM + decp + joint, fully overlapped =================
// 256 blocks x 512 threads, 1 block/CU (128KB LDS).
//  bid 0-63 : layer0 chain (r14-verified)     bid 64-127: layer1 chain (r14-verified)
//  bid 128-143: decp workers (16 x 32 cols)   bid 144-255: joint workers (16 ngroups x 7)
// Dataflow: L0 <-> L1 via tag-records (r14); decp <- h1 records; joint <- dtag + decpf.
__global__ __launch_bounds__(512) void k_mega(
    const float* __restrict__ X0,             // (B,U,4096) f32
    const unsigned short* __restrict__ W_hh0,
    const unsigned short* __restrict__ W_ih1,
    const unsigned short* __restrict__ W_hh1,
    const float* __restrict__ b_ih1,
    const float* __restrict__ b_hh1,
    unsigned int* __restrict__ exch,          // h0:[2][8192]dw, h1:+16384
    const unsigned short* __restrict__ Wdecb, // (512,1024) bf16
    float* __restrict__ decpf,                // (4,64,512) f32
    unsigned int* __restrict__ dtag,          // (64,16)
    const unsigned short* __restrict__ encpb, // (512,512) bf16
    const unsigned short* __restrict__ Woutb, // (2048,512) bf16
    const float* __restrict__ bout,           // (2048) f32
    float* __restrict__ out) {                // (32768,2048) f32
  __shared__ unsigned long long smem[16384];  // 128KB union
  int tid = threadIdx.x;
  int lane = tid & 63, w = tid >> 6;
  int bid = blockIdx.x;
  unsigned int* REC0 = exch;
  unsigned int* REC1 = exch + 16384;

  if (bid < 128) {
    // =========================== LSTM (r14 verbatim, minus hdec) ===========================
    unsigned short (*X_lds)[2064] = (unsigned short (*)[2064])smem;
    float (*red)[4][16][4] = (float (*)[4][16][4])((char*)smem + 16512);
    bool isL1 = bid >= 64;
    int bidl = bid & 63;
    int base = bidl * 16;

    bf16x8 wf[4][8];
    int ch = lane & 15;
    int klo = (lane >> 4) << 3;
    int kb = isL1 ? w * 256 : w * 128;
#pragma unroll
    for (int nt = 0; nt < 4; nt++) {
      int grow = nt * 1024 + base + ch;
      if (!isL1) {
#pragma unroll
        for (int ks = 0; ks < 4; ks++)
          wf[nt][ks] = *(const bf16x8*)(W_hh0 + (size_t)grow * 1024 + kb + ks * 32 + klo);
      } else {
#pragma unroll
        for (int ks = 0; ks < 8; ks++) {
          int k = kb + ks * 32 + klo;
          const unsigned short* src = (k < 1024) ? (W_ih1 + (size_t)grow * 1024 + k)
                                                 : (W_hh1 + (size_t)grow * 1024 + (k - 1024));
          wf[nt][ks] = *(const bf16x8*)src;
        }
      }
    }

    float creg = 0.f;
    float bs0 = 0.f, bs1 = 0.f, bs2 = 0.f, bs3 = 0.f;
    int gch = tid >> 2, gb = tid & 3;
    if (isL1 && tid < 64) {
      int c = base + gch;
      bs0 = b_ih1[c] + b_hh1[c];
      bs1 = b_ih1[1024 + c] + b_hh1[1024 + c];
      bs2 = b_ih1[2048 + c] + b_hh1[2048 + c];
      bs3 = b_ih1[3072 + c] + b_hh1[3072 + c];
    }

    int uoff[3], upb[3], us[3]; bool uneed[3];
#pragma unroll
    for (int r = 0; r < 3; r++) {
      int u = tid + r * 512;
      uneed[r] = (u < 1408);
      int uc = uneed[r] ? u : 1407;
      int pb = uc / 22;
      int s = uc - pb * 22;
      upb[r] = pb; us[r] = s;
      uoff[r] = pb * 128 + s * 4;
    }

#define STAGE_UNIT(rv, rr, off1024)                                           \
    if (uneed[rv]) {                                                          \
      int pb_ = upb[rv], s_ = us[rv];                                         \
      _Pragma("unroll")                                                       \
      for (int j_ = 0; j_ < 3; j_++) {                                        \
        int i_ = 3 * s_ + j_;                                                 \
        if (i_ < 64) {                                                        \
          union { unsigned int u; float f; } cv_; cv_.u = rr[j_];             \
          X_lds[i_ & 3][off1024 + pb_ * 16 + (i_ >> 2)] = f2bf(cv_.f);        \
        }                                                                     \
      }                                                                       \
    }

    int ar = ch & 3;
    if (!isL1) {
      for (int p = 0; p < 64; p++) {
        float xp0 = 0.f, xp1 = 0.f, xp2 = 0.f, xp3 = 0.f;
        if (tid < 64) {
          const float* x0p = X0 + ((size_t)(gb * 64 + p)) * 4096 + base + gch;
          xp0 = x0p[0]; xp1 = x0p[1024]; xp2 = x0p[2048]; xp3 = x0p[3072];
        }
        {
          unsigned int* b0 = REC0 + (unsigned)(p & 1) * 8192;
          const unsigned int* pp = REC1 + (unsigned)((p - 1) & 1) * 8192 + (tid & 63) * 128 + 3;
          unsigned expP = (p == 0) ? 0u : (unsigned)(p - 1);
          u32x4 r0, r1, r2; unsigned int pt;
          while (true) {
            spin_load3p(b0 + uoff[0], b0 + uoff[1], b0 + uoff[2], pp, r0, r1, r2, pt);
            bool ok = (!uneed[0] || r0[3] == (unsigned)p) && (!uneed[1] || r1[3] == (unsigned)p) &&
                      (!uneed[2] || r2[3] == (unsigned)p) && (pt >= expP);
            if (ok) break;
            __builtin_amdgcn_s_sleep(1);
          }
          STAGE_UNIT(0, r0, 0) STAGE_UNIT(1, r1, 0) STAGE_UNIT(2, r2, 0)
        }
        __syncthreads();
        {
          f32x4 acc[4];
#pragma unroll
          for (int nt = 0; nt < 4; nt++) acc[nt] = (f32x4){0.f, 0.f, 0.f, 0.f};
#pragma unroll
          for (int ks = 0; ks < 4; ks++) {
            bf16x8 a = *(const bf16x8*)&X_lds[ar][kb + ks * 32 + klo];
#pragma unroll
            for (int nt = 0; nt < 4; nt++)
              acc[nt] = __builtin_amdgcn_mfma_f32_16x16x32_bf16(a, wf[nt][ks], acc[nt], 0, 0, 0);
          }
          if (lane < 16) {
#pragma unroll
            for (int nt = 0; nt < 4; nt++) *(f32x4*)&red[w][nt][lane][0] = acc[nt];
          }
        }
        __syncthreads();
        if (tid < 64) {
          float g0 = 0.f, g1 = 0.f, g2 = 0.f, g3 = 0.f;
#pragma unroll
          for (int w8 = 0; w8 < 8; w8++) {
            g0 += red[w8][0][gch][gb]; g1 += red[w8][1][gch][gb];
            g2 += red[w8][2][gch][gb]; g3 += red[w8][3][gch][gb];
          }
          g0 += xp0; g1 += xp1; g2 += xp2; g3 += xp3;
          float ii = 1.f / (1.f + __expf(-g0));
          float ff = 1.f / (1.f + __expf(-g1));
          float oo = 1.f / (1.f + __expf(-g3));
          float cn = ff * creg + ii * tanhf(g2);
          creg = cn;
          float hn = oo * tanhf(cn);
          int l = tid;
          float v0 = __shfl(hn, 3 * l);
          float v1 = __shfl(hn, 3 * l + 1);
          float v2 = __shfl(hn, 3 * l + 2);
          if (l < 22) {
            unsigned tag = (unsigned)(p + 1);
            unsigned int* rec = REC0 + (tag & 1) * 8192 + bidl * 128 + l * 4;
            u32x4 d;
            d[0] = __float_as_uint(v0); d[1] = __float_as_uint(v1);
            d[2] = __float_as_uint(v2); d[3] = tag;
            store16_coh(rec, d);
          }
        }
      }
    } else {
      for (int p = 1; p <= 64; p++) {
        {
          unsigned int* b0 = REC0 + (unsigned)(p & 1) * 8192;
          unsigned int* b1 = REC1 + (unsigned)((p - 1) & 1) * 8192;
          u32x4 r0, r1, r2, r3, r4, r5;
          unsigned exp0 = (unsigned)p, exp1 = (unsigned)(p - 1);
          while (true) {
            spin_load6(b0 + uoff[0], b0 + uoff[1], b0 + uoff[2],
                       b1 + uoff[0], b1 + uoff[1], b1 + uoff[2],
                       r0, r1, r2, r3, r4, r5);
            bool ok = (!uneed[0] || (r0[3] == exp0 && r3[3] == exp1)) &&
                      (!uneed[1] || (r1[3] == exp0 && r4[3] == exp1)) &&
                      (!uneed[2] || (r2[3] == exp0 && r5[3] == exp1));
            if (ok) break;
            __builtin_amdgcn_s_sleep(1);
          }
          STAGE_UNIT(0, r0, 0) STAGE_UNIT(1, r1, 0) STAGE_UNIT(2, r2, 0)
          STAGE_UNIT(0, r3, 1024) STAGE_UNIT(1, r4, 1024) STAGE_UNIT(2, r5, 1024)
        }
        __syncthreads();
        {
          f32x4 acc[4];
#pragma unroll
          for (int nt = 0; nt < 4; nt++) acc[nt] = (f32x4){0.f, 0.f, 0.f, 0.f};
#pragma unroll
          for (int ks = 0; ks < 8; ks++) {
            bf16x8 a = *(const bf16x8*)&X_lds[ar][kb + ks * 32 + klo];
#pragma unroll
            for (int nt = 0; nt < 4; nt++)
              acc[nt] = __builtin_amdgcn_mfma_f32_16x16x32_bf16(a, wf[nt][ks], acc[nt], 0, 0, 0);
          }
          if (lane < 16) {
#pragma unroll
            for (int nt = 0; nt < 4; nt++) *(f32x4*)&red[w][nt][lane][0] = acc[nt];
          }
        }
        __syncthreads();
        if (tid < 64) {
          float g0 = 0.f, g1 = 0.f, g2 = 0.f, g3 = 0.f;
#pragma unroll
          for (int w8 = 0; w8 < 8; w8++) {
            g0 += red[w8][0][gch][gb]; g1 += red[w8][1][gch][gb];
            g2 += red[w8][2][gch][gb]; g3 += red[w8][3][gch][gb];
          }
          g0 += bs0; g1 += bs1; g2 += bs2; g3 += bs3;
          float ii = 1.f / (1.f + __expf(-g0));
          float ff = 1.f / (1.f + __expf(-g1));
          float oo = 1.f / (1.f + __expf(-g3));
          float cn = ff * creg + ii * tanhf(g2);
          creg = cn;
          float hn = oo * tanhf(cn);
          int l = tid;
          float v0 = __shfl(hn, 3 * l);
          float v1 = __shfl(hn, 3 * l + 1);
          float v2 = __shfl(hn, 3 * l + 2);
          if (l < 22) {
            unsigned tag = (unsigned)p;
            unsigned int* rec = REC1 + (tag & 1) * 8192 + bidl * 128 + l * 4;
            u32x4 d;
            d[0] = __float_as_uint(v0); d[1] = __float_as_uint(v1);
            d[2] = __float_as_uint(v2); d[3] = tag;
            store16_coh(rec, d);
          }
        }
      }
    }
  } else if (bid < 144) {
    // =========================== decp workers: decp = h1 @ Wdec^T ===========================
    unsigned short (*X_lds)[2064] = (unsigned short (*)[2064])smem;
    float (*red)[4][16][4] = (float (*)[4][16][4])((char*)smem + 16512);
    int d = bid - 128;                        // owns dec-cols [d*32, d*32+32)
    int ch = lane & 15;
    int klo = (lane >> 4) << 3;
    int kb = w * 128;
    bf16x8 wfd[2][4];
#pragma unroll
    for (int nt = 0; nt < 2; nt++) {
      int grow = d * 32 + nt * 16 + ch;
#pragma unroll
      for (int ks = 0; ks < 4; ks++)
        wfd[nt][ks] = *(const bf16x8*)(Wdecb + (size_t)grow * 1024 + kb + ks * 32 + klo);
    }
    int uoff[3], upb[3], us[3]; bool uneed[3];
#pragma unroll
    for (int r = 0; r < 3; r++) {
      int u = tid + r * 512;
      uneed[r] = (u < 1408);
      int uc = uneed[r] ? u : 1407;
      int pb = uc / 22;
      int s = uc - pb * 22;
      upb[r] = pb; us[r] = s;
      uoff[r] = pb * 128 + s * 4;
    }
    int ar = ch & 3;
    for (int u = 0; u < 64; u++) {
      unsigned expt = (unsigned)(u + 1);
      {
        unsigned int* b1 = REC1 + (expt & 1) * 8192;
        u32x4 r0, r1, r2; unsigned int pt;
        while (true) {
          spin_load3p(b1 + uoff[0], b1 + uoff[1], b1 + uoff[2], b1 + uoff[0] + 3, r0, r1, r2, pt);
          bool ok = (!uneed[0] || r0[3] == expt) && (!uneed[1] || r1[3] == expt) &&
                    (!uneed[2] || r2[3] == expt);
          if (ok) break;
          __builtin_amdgcn_s_sleep(1);
        }
        STAGE_UNIT(0, r0, 0) STAGE_UNIT(1, r1, 0) STAGE_UNIT(2, r2, 0)
      }
      __syncthreads();
      {
        f32x4 acc[2];
#pragma unroll
        for (int nt = 0; nt < 2; nt++) acc[nt] = (f32x4){0.f, 0.f, 0.f, 0.f};
#pragma unroll
        for (int ks = 0; ks < 4; ks++) {
          bf16x8 a = *(const bf16x8*)&X_lds[ar][kb + ks * 32 + klo];
#pragma unroll
          for (int nt = 0; nt < 2; nt++)
            acc[nt] = __builtin_amdgcn_mfma_f32_16x16x32_bf16(a, wfd[nt][ks], acc[nt], 0, 0, 0);
        }
        if (lane < 16) {
#pragma unroll
          for (int nt = 0; nt < 2; nt++) *(f32x4*)&red[w][nt][lane][0] = acc[nt];
        }
      }
      __syncthreads();
      if (tid < 128) {
        int nt = tid >> 6, c = (tid >> 2) & 15, b = tid & 3;
        float s = 0.f;
#pragma unroll
        for (int w8 = 0; w8 < 8; w8++) s += red[w8][nt][c][b];
        __hip_atomic_store(&decpf[((size_t)(b * 64 + u)) * 512 + d * 32 + nt * 16 + c], s,
                           __ATOMIC_RELAXED, __HIP_MEMORY_SCOPE_AGENT);
      }
      asm volatile("s_waitcnt vmcnt(0)" ::: "memory");
      __syncthreads();
      if (tid == 0)
        __hip_atomic_store(&dtag[u * 16 + d], 1u, __ATOMIC_RELAXED, __HIP_MEMORY_SCOPE_AGENT);
      __syncthreads();
    }
  } else {
    // ================ joint workers: out[.,.,u,cols] = tanh(enc+dec) @ Wout^T ===============
    unsigned short (*Wls)[8192] = (unsigned short (*)[8192])smem;  // 128KB: ngroup's Wout slice
    int jid = bid - 144;
    int g = jid / 7, r = jid % 7;             // ngroup g (128 cols), u-stripe r
#pragma unroll
    for (int kc = 0; kc < 8; kc++) {
      unsigned short* dst = &Wls[kc][0];
#pragma unroll
      for (int q = 0; q < 2; q++) {
        int idx = tid + q * 512;
        int n = idx >> 3, sl = idx & 7;
        int ss = sl ^ (n & 7);
        gload_lds16(Woutb + (size_t)(g * 128 + n) * 512 + kc * 64 + ss * 8, dst + idx * 8);
      }
    }
    float bb[8];
#pragma unroll
    for (int nf = 0; nf < 8; nf++) bb[nf] = bout[g * 128 + nf * 16 + (lane & 15)];
    asm volatile("s_waitcnt vmcnt(0)" ::: "memory");
    __syncthreads();

    for (int u = r; u < 64; u += 7) {
      // poll all 16 dtag[u][*]
      while (true) {
        unsigned t = 1u;
        if (lane < 16)
          t = __hip_atomic_load(&dtag[u * 16 + lane], __ATOMIC_RELAXED, __HIP_MEMORY_SCOPE_AGENT);
        if (__all(t == 1u)) break;
        __builtin_amdgcn_s_sleep(8);
      }
      // wave computes rows [w*64, w*64+64) of the 512 (b,t) rows
      f32x4 acc[4][8];
#pragma unroll
      for (int mf = 0; mf < 4; mf++)
#pragma unroll
        for (int nf = 0; nf < 8; nf++) acc[mf][nf] = (f32x4){0.f, 0.f, 0.f, 0.f};
#pragma unroll
      for (int ks = 0; ks < 16; ks++) {
        int k0 = ks * 32 + ((lane >> 4) << 3);
        bf16x8 a[4];
#pragma unroll
        for (int mf = 0; mf < 4; mf++) {
          int row = w * 64 + mf * 16 + (lane & 15);     // bt index
          int b = row >> 7;
          bf16x8 ev = *(const bf16x8*)(encpb + (size_t)row * 512 + k0);
          const float* dp = decpf + ((size_t)(b * 64 + u)) * 512 + k0;
          f32x4 d0 = *(const f32x4*)dp;
          f32x4 d1 = *(const f32x4*)(dp + 4);
          bf16x8 v;
#pragma unroll
          for (int j = 0; j < 4; j++) {
            float x = bfu2f((unsigned short)ev[j]) + d0[j];
            float e = __expf(x + x);
            v[j] = (short)f2bf(1.f - 2.f / (e + 1.f));
          }
#pragma unroll
          for (int j = 0; j < 4; j++) {
            float x = bfu2f((unsigned short)ev[4 + j]) + d1[j];
            float e = __expf(x + x);
            v[4 + j] = (short)f2bf(1.f - 2.f / (e + 1.f));
          }
          a[mf] = v;
        }
        const unsigned short* Wb = &Wls[ks >> 1][0];
        int slot = (ks & 1) * 4 + (lane >> 4);
#pragma unroll
        for (int nf = 0; nf < 8; nf++) {
          int nl = nf * 16 + (lane & 15);
          int phys = slot ^ (nl & 7);
          bf16x8 bfr = *(const bf16x8*)(Wb + nl * 64 + phys * 8);
#pragma unroll
          for (int mf = 0; mf < 4; mf++)
            acc[mf][nf] = __builtin_amdgcn_mfma_f32_16x16x32_bf16(a[mf], bfr, acc[mf][nf], 0, 0, 0);
        }
      }
#pragma unroll
      for (int mf = 0; mf < 4; mf++) {
        int rb = w * 64 + mf * 16 + ((lane >> 4) << 2);
#pragma unroll
        for (int nf = 0; nf < 8; nf++) {
          int o = g * 128 + nf * 16 + (lane & 15);
          float bias = bb[nf];
#pragma unroll
          for (int q = 0; q < 4; q++)
            __builtin_nontemporal_store(acc[mf][nf][q] + bias,
                                        &out[((size_t)(rb + q) * 64 + u) * 2048 + o]);
        }
      }
    }
  }
#undef STAGE_UNIT
}

// ---------------- launch ----------------
extern "C" void kernel_launch(void* const* d_in, const int* in_sizes, int n_in,
                              void* d_out, int out_size, void* d_ws, size_t ws_size,
                              hipStream_t stream) {
  const float* hs   = (const float*)d_in[0];
  const int*   ys   = (const int*)d_in[1];
  const float* emb  = (const float*)d_in[2];
  const float* Wih0 = (const float*)d_in[3];
  const float* Whh0 = (const float*)d_in[4];
  const float* bih0 = (const float*)d_in[5];
  const float* bhh0 = (const float*)d_in[6];
  const float* Wih1 = (const float*)d_in[7];
  const float* Whh1 = (const float*)d_in[8];
  const float* bih1 = (const float*)d_in[9];
  const float* bhh1 = (const float*)d_in[10];
  const float* Wenc = (const float*)d_in[11];
  const float* benc = (const float*)d_in[12];
  const float* Wdec = (const float*)d_in[13];
  const float* Wout = (const float*)d_in[14];
  const float* bout = (const float*)d_in[15];

  // Workspace map (no overlap needed; total 34,213,888 B):
  char* ws = (char*)d_ws;
  unsigned short* Woutb = (unsigned short*)(ws + 0);         // 2,097,152
  unsigned short* Wdecb = (unsigned short*)(ws + 2097152);   // 1,048,576
  unsigned short* encpb = (unsigned short*)(ws + 3145728);   //   524,288
  unsigned int*   exch  = (unsigned int*)(ws + 3670016);     //   131,072
  unsigned int*   dtag  = (unsigned int*)(ws + 3801088);     //     4,096
  float*          decpf = (float*)(ws + 3805184);            //   524,288
  float*          eys   = (float*)(ws + 4329472);            //   524,288
  float*          X0    = (float*)(ws + 4853760);            // 4,194,304
  unsigned short* Whh0b = (unsigned short*)(ws + 9048064);   // 8,388,608
  unsigned short* Wih1b = (unsigned short*)(ws + 17436672);  // 8,388,608
  unsigned short* Whh1b = (unsigned short*)(ws + 25825280);  // 8,388,608 -> 34,213,888
  float*          out   = (float*)d_out;

  k_cvt<<<6912, 256, 0, stream>>>(Whh0, Wih1, Whh1, Wout, Wdec,
                                  Whh0b, Wih1b, Whh1b, Woutb, Wdecb);
  k_prep<<<64, 256, 0, stream>>>(ys, emb, eys, exch, dtag);
  // X0 = eys @ Wih0^T + bih0 + bhh0   (f32 out; M=256, N=4096, K=512)
  k_gemm_bias<<<256, 256, 0, stream>>>(eys, Wih0, bih0, bhh0, X0, 0, 256, 4096, 512);
  // encpb = bf16(hs @ Wenc^T + benc)  (M=512, N=512, K=512)
  k_gemm_bias<<<64, 256, 0, stream>>>(hs, Wenc, benc, nullptr, encpb, 1, 512, 512, 512);
  // mega: LSTM chains + decp workers + joint workers, all overlapped
  k_mega<<<256, 512, 0, stream>>>(X0, Whh0b, Wih1b, Whh1b, bih1, bhh1, exch,
                                  Wdecb, decpf, dtag, encpb, Woutb, bout, out);
}

// Round 16
// 534.982 us; speedup vs baseline: 2.3552x; 2.3552x over previous
//
#include <hip/hip_runtime.h>
#include <stdint.h>

typedef short bf16x8 __attribute__((ext_vector_type(8)));
typedef float f32x4 __attribute__((ext_vector_type(4)));
typedef unsigned int u32x4 __attribute__((ext_vector_type(4)));

__device__ __forceinline__ unsigned short f2bf(float f) {
  union { float f; unsigned int i; } v; v.f = f;
  unsigned int r = v.i + 0x7FFF + ((v.i >> 16) & 1);
  return (unsigned short)(r >> 16);
}
__device__ __forceinline__ float bfu2f(unsigned short u) {
  union { unsigned int i; float f; } v; v.i = ((unsigned int)u) << 16; return v.f;
}
__device__ __forceinline__ void gload_lds16(const void* g, void* l) {
  __builtin_amdgcn_global_load_lds(
      (const __attribute__((address_space(1))) unsigned int*)g,
      (__attribute__((address_space(3))) unsigned int*)l,
      16, 0, 0);
}
// coherent (IC-level) 16B store: single instruction => tag+data commit atomically
__device__ __forceinline__ void store16_coh(unsigned int* p, u32x4 v) {
  asm volatile("global_store_dwordx4 %0, %1, off sc0 sc1" :: "v"(p), "v"(v) : "memory");
}
__device__ __forceinline__ void spin_load6(const unsigned int* p0, const unsigned int* p1,
                                           const unsigned int* p2, const unsigned int* p3,
                                           const unsigned int* p4, const unsigned int* p5,
                                           u32x4& r0, u32x4& r1, u32x4& r2,
                                           u32x4& r3, u32x4& r4, u32x4& r5) {
  asm volatile(
      "global_load_dwordx4 %0, %6, off sc0 sc1\n\t"
      "global_load_dwordx4 %1, %7, off sc0 sc1\n\t"
      "global_load_dwordx4 %2, %8, off sc0 sc1\n\t"
      "global_load_dwordx4 %3, %9, off sc0 sc1\n\t"
      "global_load_dwordx4 %4, %10, off sc0 sc1\n\t"
      "global_load_dwordx4 %5, %11, off sc0 sc1\n\t"
      "s_waitcnt vmcnt(0)"
      : "=&v"(r0), "=&v"(r1), "=&v"(r2), "=&v"(r3), "=&v"(r4), "=&v"(r5)
      : "v"(p0), "v"(p1), "v"(p2), "v"(p3), "v"(p4), "v"(p5)
      : "memory");
}
// 3 record loads + 1 probe-tag load (L0 spin body)
__device__ __forceinline__ void spin_load3p(const unsigned int* p0, const unsigned int* p1,
                                            const unsigned int* p2, const unsigned int* pp,
                                            u32x4& r0, u32x4& r1, u32x4& r2, unsigned int& pt) {
  asm volatile(
      "global_load_dwordx4 %0, %4, off sc0 sc1\n\t"
      "global_load_dwordx4 %1, %5, off sc0 sc1\n\t"
      "global_load_dwordx4 %2, %6, off sc0 sc1\n\t"
      "global_load_dword %3, %7, off sc0 sc1\n\t"
      "s_waitcnt vmcnt(0)"
      : "=&v"(r0), "=&v"(r1), "=&v"(r2), "=&v"(pt)
      : "v"(p0), "v"(p1), "v"(p2), "v"(pp)
      : "memory");
}

// ---------------- convert f32 weights -> bf16 (Whh0, Wih1, Whh1, Wout) ----------------
__global__ __launch_bounds__(256) void k_cvt(const float* __restrict__ s0, const float* __restrict__ s1,
                                             const float* __restrict__ s2, const float* __restrict__ s3,
                                             unsigned short* __restrict__ d0, unsigned short* __restrict__ d1,
                                             unsigned short* __restrict__ d2, unsigned short* __restrict__ d3) {
  int j = blockIdx.x * 256 + threadIdx.x;   // 6656*256 = 1,703,936 vec8 jobs exactly
  const float* s; unsigned short* d; int o;
  if (j < 524288)       { s = s0; d = d0; o = j; }
  else if (j < 1048576) { s = s1; d = d1; o = j - 524288; }
  else if (j < 1572864) { s = s2; d = d2; o = j - 1048576; }
  else                  { s = s3; d = d3; o = j - 1572864; }
  size_t off = (size_t)o * 8;
  f32x4 v0 = *(const f32x4*)(s + off);
  f32x4 v1 = *(const f32x4*)(s + off + 4);
  bf16x8 r;
#pragma unroll
  for (int k = 0; k < 4; k++) { r[k] = (short)f2bf(v0[k]); r[4 + k] = (short)f2bf(v1[k]); }
  *(bf16x8*)(d + off) = r;
}

// ---------------- prep: embedding gather (f32) + zero BOTH parities of exchange -------
__global__ __launch_bounds__(256) void k_prep(const int* __restrict__ ys,
                                              const float* __restrict__ embed,
                                              float* __restrict__ eys,
                                              unsigned int* __restrict__ exch) {
  int idx = blockIdx.x * 256 + threadIdx.x;   // 16384 threads
  int row = idx >> 6;
  int e = (idx & 63) * 8;
  int y = ys[row];
  f32x4 v0 = {0.f, 0.f, 0.f, 0.f}, v1 = {0.f, 0.f, 0.f, 0.f};
  if (y != 0) {
    v0 = *(const f32x4*)(embed + (size_t)y * 512 + e);
    v1 = *(const f32x4*)(embed + (size_t)y * 512 + e + 4);
  }
  *(f32x4*)(eys + (size_t)row * 512 + e) = v0;
  *(f32x4*)(eys + (size_t)row * 512 + e + 4) = v1;
  exch[idx] = 0u;                 // 32768 dwords: h0[2][8192] + h1[2][8192]
  exch[idx + 16384] = 0u;
}

// -------- generic small GEMM: C = A(f32 MxK) @ W(f32 NxK)^T + b1 + b2; C f32 or bf16 ----
__global__ __launch_bounds__(256) void k_gemm_bias(const float* __restrict__ A,
                                                   const float* __restrict__ W,
                                                   const float* __restrict__ b1,
                                                   const float* __restrict__ b2,
                                                   void* __restrict__ Cout, int obf,
                                                   int M, int N, int K) {
  __shared__ unsigned short Als[64][40];
  __shared__ unsigned short Wls[64][40];
  int tid = threadIdx.x;
  int lane = tid & 63, wid = tid >> 6;
  int mtiles = M >> 6;
  int mt = blockIdx.x % mtiles, nt = blockIdx.x / mtiles;
  int srow = tid >> 2, sseg = tid & 3;
  f32x4 acc[4];
#pragma unroll
  for (int nf = 0; nf < 4; nf++) acc[nf] = (f32x4){0.f, 0.f, 0.f, 0.f};

  for (int kc = 0; kc < K; kc += 32) {
    const float* ap = A + (size_t)(mt * 64 + srow) * K + kc + sseg * 8;
    const float* wp = W + (size_t)(nt * 64 + srow) * K + kc + sseg * 8;
    f32x4 a0 = *(const f32x4*)ap, a1 = *(const f32x4*)(ap + 4);
    f32x4 w0 = *(const f32x4*)wp, w1 = *(const f32x4*)(wp + 4);
    bf16x8 av, wv;
#pragma unroll
    for (int k = 0; k < 4; k++) {
      av[k] = (short)f2bf(a0[k]); av[4 + k] = (short)f2bf(a1[k]);
      wv[k] = (short)f2bf(w0[k]); wv[4 + k] = (short)f2bf(w1[k]);
    }
    __syncthreads();
    *(bf16x8*)(&Als[srow][sseg * 8]) = av;
    *(bf16x8*)(&Wls[srow][sseg * 8]) = wv;
    __syncthreads();
    bf16x8 af = *(const bf16x8*)(&Als[wid * 16 + (lane & 15)][(lane >> 4) * 8]);
#pragma unroll
    for (int nf = 0; nf < 4; nf++) {
      bf16x8 bf = *(const bf16x8*)(&Wls[nf * 16 + (lane & 15)][(lane >> 4) * 8]);
      acc[nf] = __builtin_amdgcn_mfma_f32_16x16x32_bf16(af, bf, acc[nf], 0, 0, 0);
    }
  }
  int rloc = (lane >> 4) * 4;
  int col0 = lane & 15;
#pragma unroll
  for (int nf = 0; nf < 4; nf++) {
    int n = nt * 64 + nf * 16 + col0;
    float bias = 0.f;
    if (b1) bias += b1[n];
    if (b2) bias += b2[n];
#pragma unroll
    for (int r = 0; r < 4; r++) {
      int m = mt * 64 + wid * 16 + rloc + r;
      float v = acc[nf][r] + bias;
      if (obf) ((unsigned short*)Cout)[(size_t)m * N + n] = f2bf(v);
      else     ((float*)Cout)[(size_t)m * N + n] = v;
    }
  }
}

// ---------------- fused LSTM v5: split L0/L1 blocks, decoupled chains (r14 verbatim) ----
__global__ __launch_bounds__(512) void k_lstm_fused(
    const float* __restrict__ X0,            // (B,U,4096)
    float* __restrict__ hdec,                // (B,U,1024) f32
    const unsigned short* __restrict__ W_hh0,
    const unsigned short* __restrict__ W_ih1,
    const unsigned short* __restrict__ W_hh1,
    const float* __restrict__ b_ih1,
    const float* __restrict__ b_hh1,
    unsigned int* __restrict__ exch) {       // h0:[2][8192]dw, h1:+16384:[2][8192]dw
  __shared__ unsigned short X_lds[4][2064];
  __shared__ float red[8][4][16][4];
  int tid = threadIdx.x;
  int lane = tid & 63, w = tid >> 6;
  bool isL1 = blockIdx.x >= 64;
  int bidl = blockIdx.x & 63;
  int base = bidl * 16;
  unsigned int* REC0 = exch;
  unsigned int* REC1 = exch + 16384;

  bf16x8 wf[4][8];                           // L0 uses [.][0..3]
  int ch = lane & 15;
  int klo = (lane >> 4) << 3;
  int kb = isL1 ? w * 256 : w * 128;
#pragma unroll
  for (int nt = 0; nt < 4; nt++) {
    int grow = nt * 1024 + base + ch;
    if (!isL1) {
#pragma unroll
      for (int ks = 0; ks < 4; ks++)
        wf[nt][ks] = *(const bf16x8*)(W_hh0 + (size_t)grow * 1024 + kb + ks * 32 + klo);
    } else {
#pragma unroll
      for (int ks = 0; ks < 8; ks++) {
        int k = kb + ks * 32 + klo;
        const unsigned short* src = (k < 1024) ? (W_ih1 + (size_t)grow * 1024 + k)
                                               : (W_hh1 + (size_t)grow * 1024 + (k - 1024));
        wf[nt][ks] = *(const bf16x8*)src;
      }
    }
  }

  float creg = 0.f;
  float bs0 = 0.f, bs1 = 0.f, bs2 = 0.f, bs3 = 0.f;
  int gch = tid >> 2, gb = tid & 3;
  if (isL1 && tid < 64) {
    int c = base + gch;
    bs0 = b_ih1[c] + b_hh1[c];
    bs1 = b_ih1[1024 + c] + b_hh1[1024 + c];
    bs2 = b_ih1[2048 + c] + b_hh1[2048 + c];
    bs3 = b_ih1[3072 + c] + b_hh1[3072 + c];
  }

  int uoff[3], upb[3], us[3]; bool uneed[3];
#pragma unroll
  for (int r = 0; r < 3; r++) {
    int u = tid + r * 512;
    uneed[r] = (u < 1408);
    int uc = uneed[r] ? u : 1407;
    int pb = uc / 22;
    int s = uc - pb * 22;
    upb[r] = pb; us[r] = s;
    uoff[r] = pb * 128 + s * 4;
  }

#define STAGE_UNIT(rv, rr, off1024)                                           \
  if (uneed[rv]) {                                                            \
    int pb_ = upb[rv], s_ = us[rv];                                           \
    _Pragma("unroll")                                                         \
    for (int j_ = 0; j_ < 3; j_++) {                                          \
      int i_ = 3 * s_ + j_;                                                   \
      if (i_ < 64) {                                                          \
        union { unsigned int u; float f; } cv_; cv_.u = rr[j_];               \
        X_lds[i_ & 3][off1024 + pb_ * 16 + (i_ >> 2)] = f2bf(cv_.f);          \
      }                                                                       \
    }                                                                         \
  }

  int ar = ch & 3;
  if (!isL1) {
    for (int p = 0; p < 64; p++) {
      float xp0 = 0.f, xp1 = 0.f, xp2 = 0.f, xp3 = 0.f;
      if (tid < 64) {
        const float* x0p = X0 + ((size_t)(gb * 64 + p)) * 4096 + base + gch;
        xp0 = x0p[0]; xp1 = x0p[1024]; xp2 = x0p[2048]; xp3 = x0p[3072];
      }
      {
        unsigned int* b0 = REC0 + (unsigned)(p & 1) * 8192;
        const unsigned int* pp = REC1 + (unsigned)((p - 1) & 1) * 8192 + (tid & 63) * 128 + 3;
        unsigned expP = (p == 0) ? 0u : (unsigned)(p - 1);
        u32x4 r0, r1, r2; unsigned int pt;
        while (true) {
          spin_load3p(b0 + uoff[0], b0 + uoff[1], b0 + uoff[2], pp, r0, r1, r2, pt);
          bool ok = (!uneed[0] || r0[3] == (unsigned)p) && (!uneed[1] || r1[3] == (unsigned)p) &&
                    (!uneed[2] || r2[3] == (unsigned)p) && (pt >= expP);
          if (ok) break;
          __builtin_amdgcn_s_sleep(1);
        }
        STAGE_UNIT(0, r0, 0) STAGE_UNIT(1, r1, 0) STAGE_UNIT(2, r2, 0)
      }
      __syncthreads();
      {
        f32x4 acc[4];
#pragma unroll
        for (int nt = 0; nt < 4; nt++) acc[nt] = (f32x4){0.f, 0.f, 0.f, 0.f};
#pragma unroll
        for (int ks = 0; ks < 4; ks++) {
          bf16x8 a = *(const bf16x8*)&X_lds[ar][kb + ks * 32 + klo];
#pragma unroll
          for (int nt = 0; nt < 4; nt++)
            acc[nt] = __builtin_amdgcn_mfma_f32_16x16x32_bf16(a, wf[nt][ks], acc[nt], 0, 0, 0);
        }
        if (lane < 16) {
#pragma unroll
          for (int nt = 0; nt < 4; nt++) *(f32x4*)&red[w][nt][lane][0] = acc[nt];
        }
      }
      __syncthreads();
      if (tid < 64) {
        float g0 = 0.f, g1 = 0.f, g2 = 0.f, g3 = 0.f;
#pragma unroll
        for (int w8 = 0; w8 < 8; w8++) {
          g0 += red[w8][0][gch][gb]; g1 += red[w8][1][gch][gb];
          g2 += red[w8][2][gch][gb]; g3 += red[w8][3][gch][gb];
        }
        g0 += xp0; g1 += xp1; g2 += xp2; g3 += xp3;
        float ii = 1.f / (1.f + __expf(-g0));
        float ff = 1.f / (1.f + __expf(-g1));
        float oo = 1.f / (1.f + __expf(-g3));
        float cn = ff * creg + ii * tanhf(g2);
        creg = cn;
        float hn = oo * tanhf(cn);
        int l = tid;
        float v0 = __shfl(hn, 3 * l);
        float v1 = __shfl(hn, 3 * l + 1);
        float v2 = __shfl(hn, 3 * l + 2);
        if (l < 22) {
          unsigned tag = (unsigned)(p + 1);
          unsigned int* rec = REC0 + (tag & 1) * 8192 + bidl * 128 + l * 4;
          u32x4 d;
          d[0] = __float_as_uint(v0); d[1] = __float_as_uint(v1);
          d[2] = __float_as_uint(v2); d[3] = tag;
          store16_coh(rec, d);
        }
      }
    }
  } else {
    for (int p = 1; p <= 64; p++) {
      {
        unsigned int* b0 = REC0 + (unsigned)(p & 1) * 8192;
        unsigned int* b1 = REC1 + (unsigned)((p - 1) & 1) * 8192;
        u32x4 r0, r1, r2, r3, r4, r5;
        unsigned exp0 = (unsigned)p, exp1 = (unsigned)(p - 1);
        while (true) {
          spin_load6(b0 + uoff[0], b0 + uoff[1], b0 + uoff[2],
                     b1 + uoff[0], b1 + uoff[1], b1 + uoff[2],
                     r0, r1, r2, r3, r4, r5);
          bool ok = (!uneed[0] || (r0[3] == exp0 && r3[3] == exp1)) &&
                    (!uneed[1] || (r1[3] == exp0 && r4[3] == exp1)) &&
                    (!uneed[2] || (r2[3] == exp0 && r5[3] == exp1));
          if (ok) break;
          __builtin_amdgcn_s_sleep(1);
        }
        STAGE_UNIT(0, r0, 0) STAGE_UNIT(1, r1, 0) STAGE_UNIT(2, r2, 0)
        STAGE_UNIT(0, r3, 1024) STAGE_UNIT(1, r4, 1024) STAGE_UNIT(2, r5, 1024)
      }
      __syncthreads();
      {
        f32x4 acc[4];
#pragma unroll
        for (int nt = 0; nt < 4; nt++) acc[nt] = (f32x4){0.f, 0.f, 0.f, 0.f};
#pragma unroll
        for (int ks = 0; ks < 8; ks++) {
          bf16x8 a = *(const bf16x8*)&X_lds[ar][kb + ks * 32 + klo];
#pragma unroll
          for (int nt = 0; nt < 4; nt++)
            acc[nt] = __builtin_amdgcn_mfma_f32_16x16x32_bf16(a, wf[nt][ks], acc[nt], 0, 0, 0);
        }
        if (lane < 16) {
#pragma unroll
          for (int nt = 0; nt < 4; nt++) *(f32x4*)&red[w][nt][lane][0] = acc[nt];
        }
      }
      __syncthreads();
      if (tid < 64) {
        float g0 = 0.f, g1 = 0.f, g2 = 0.f, g3 = 0.f;
#pragma unroll
        for (int w8 = 0; w8 < 8; w8++) {
          g0 += red[w8][0][gch][gb]; g1 += red[w8][1][gch][gb];
          g2 += red[w8][2][gch][gb]; g3 += red[w8][3][gch][gb];
        }
        g0 += bs0; g1 += bs1; g2 += bs2; g3 += bs3;
        float ii = 1.f / (1.f + __expf(-g0));
        float ff = 1.f / (1.f + __expf(-g1));
        float oo = 1.f / (1.f + __expf(-g3));
        float cn = ff * creg + ii * tanhf(g2);
        creg = cn;
        float hn = oo * tanhf(cn);
        hdec[((size_t)(gb * 64 + (p - 1))) * 1024 + base + gch] = hn;
        int l = tid;
        float v0 = __shfl(hn, 3 * l);
        float v1 = __shfl(hn, 3 * l + 1);
        float v2 = __shfl(hn, 3 * l + 2);
        if (l < 22) {
          unsigned tag = (unsigned)p;
          unsigned int* rec = REC1 + (tag & 1) * 8192 + bidl * 128 + l * 4;
          u32x4 d;
          d[0] = __float_as_uint(v0); d[1] = __float_as_uint(v1);
          d[2] = __float_as_uint(v2); d[3] = tag;
          store16_coh(rec, d);
        }
      }
    }
  }
#undef STAGE_UNIT
}

// ---------------- k_z: Z[m][k] = tanh(encp[b,t,k] + decp[b,u,k]) as bf16 --------------
__global__ __launch_bounds__(256) void k_z(const unsigned short* __restrict__ encpb, // (512,512) bf16
                                           const unsigned short* __restrict__ decpb, // (256,512) bf16
                                           unsigned short* __restrict__ Z) {
  int idx = blockIdx.x * 256 + threadIdx.x;   // 2,097,152 jobs (8192 blocks)
  int m = idx >> 6;
  int k0 = (idx & 63) * 8;
  int bt = m >> 6;                            // b*128+t
  int b = m >> 13, u = m & 63;
  bf16x8 ev = *(const bf16x8*)(encpb + (size_t)bt * 512 + k0);
  bf16x8 dv = *(const bf16x8*)(decpb + (size_t)(b * 64 + u) * 512 + k0);
  bf16x8 r;
#pragma unroll
  for (int j = 0; j < 8; j++) {
    float x = bfu2f((unsigned short)ev[j]) + bfu2f((unsigned short)dv[j]);
    float e = __expf(x + x);
    r[j] = (short)f2bf(1.f - 2.f / (e + 1.f));
  }
  *(bf16x8*)(Z + (size_t)m * 512 + k0) = r;
}

// ------ k_gemm_out v2: 512 blocks (16 m-parts x 32 n-groups of 64 cols), 2 blocks/CU ----
// Block stages its 64-col Wout slice (64KB) once into LDS; streams 2048 contiguous Z rows.
__global__ __launch_bounds__(512, 2) void k_gemm_out(const unsigned short* __restrict__ Z,    // (32768,512) bf16
                                                     const unsigned short* __restrict__ Wout, // (2048,512) bf16
                                                     const float* __restrict__ bout,          // (2048) f32
                                                     float* __restrict__ out) {               // (32768,2048) f32
  __shared__ unsigned short Wls[8][4096];   // 8 k-chunks x (64 n-rows x 64 k, swizzled) = 64KB
  int tid = threadIdx.x;
  int lane = tid & 63, wid = tid >> 6;
  int bid = blockIdx.x;
  int mpart = bid & 15, g = bid >> 4;       // g: 0..31, 64 cols each

  // ---- stage Wout slice once (8 gload_lds16 per thread) ----
#pragma unroll
  for (int kc = 0; kc < 8; kc++) {
    int n = tid >> 3, sl = tid & 7;
    int ss = sl ^ (n & 7);
    gload_lds16(Wout + (size_t)(g * 64 + n) * 512 + kc * 64 + ss * 8, &Wls[kc][tid * 8]);
  }
  float bb[4];
#pragma unroll
  for (int nf = 0; nf < 4; nf++) bb[nf] = bout[g * 64 + nf * 16 + (lane & 15)];
  asm volatile("s_waitcnt vmcnt(0)" ::: "memory");
  __syncthreads();

  int rowwave = mpart * 2048 + wid * 256;   // wave's 256 contiguous bt*64+u rows
  int ocol0 = g * 64;
  for (int mg = 0; mg < 4; mg++) {
    int rowbase = rowwave + mg * 64;
    f32x4 acc[4][4];
#pragma unroll
    for (int mf = 0; mf < 4; mf++)
#pragma unroll
      for (int nf = 0; nf < 4; nf++) acc[mf][nf] = (f32x4){0.f, 0.f, 0.f, 0.f};

#pragma unroll
    for (int ks = 0; ks < 16; ks++) {
      bf16x8 a[4];
#pragma unroll
      for (int mf = 0; mf < 4; mf++) {
        int r = rowbase + mf * 16 + (lane & 15);
        a[mf] = *(const bf16x8*)(Z + (size_t)r * 512 + ks * 32 + ((lane >> 4) << 3));
      }
      const unsigned short* Wb = &Wls[ks >> 1][0];
      int slot = (ks & 1) * 4 + (lane >> 4);
#pragma unroll
      for (int nf = 0; nf < 4; nf++) {
        int nl = nf * 16 + (lane & 15);
        int phys = slot ^ (nl & 7);
        bf16x8 bfr = *(const bf16x8*)(Wb + nl * 64 + phys * 8);
#pragma unroll
        for (int mf = 0; mf < 4; mf++)
          acc[mf][nf] = __builtin_amdgcn_mfma_f32_16x16x32_bf16(a[mf], bfr, acc[mf][nf], 0, 0, 0);
      }
    }
#pragma unroll
    for (int mf = 0; mf < 4; mf++) {
      int rb = rowbase + mf * 16 + ((lane >> 4) << 2);
#pragma unroll
      for (int nf = 0; nf < 4; nf++) {
        int o = ocol0 + nf * 16 + (lane & 15);
        float bias = bb[nf];
#pragma unroll
        for (int q = 0; q < 4; q++)
          __builtin_nontemporal_store(acc[mf][nf][q] + bias, &out[(size_t)(rb + q) * 2048 + o]);
      }
    }
  }
}

// ---------------- launch ----------------
extern "C" void kernel_launch(void* const* d_in, const int* in_sizes, int n_in,
                              void* d_out, int out_size, void* d_ws, size_t ws_size,
                              hipStream_t stream) {
  const float* hs   = (const float*)d_in[0];
  const int*   ys   = (const int*)d_in[1];
  const float* emb  = (const float*)d_in[2];
  const float* Wih0 = (const float*)d_in[3];
  const float* Whh0 = (const float*)d_in[4];
  const float* bih0 = (const float*)d_in[5];
  const float* bhh0 = (const float*)d_in[6];
  const float* Wih1 = (const float*)d_in[7];
  const float* Whh1 = (const float*)d_in[8];
  const float* bih1 = (const float*)d_in[9];
  const float* bhh1 = (const float*)d_in[10];
  const float* Wenc = (const float*)d_in[11];
  const float* benc = (const float*)d_in[12];
  const float* Wdec = (const float*)d_in[13];
  const float* Wout = (const float*)d_in[14];
  const float* bout = (const float*)d_in[15];

  // Workspace map (liveness-overlapped, r14-identical):
  char* ws = (char*)d_ws;
  unsigned short* Woutb = (unsigned short*)(ws + 0);
  unsigned short* encpb = (unsigned short*)(ws + 2097152);
  unsigned short* decpb = (unsigned short*)(ws + 2621440);
  unsigned int*   exch  = (unsigned int*)(ws + 2883584);
  unsigned short* Z     = (unsigned short*)(ws + 3031040);
  float*          eys   = (float*)(ws + 3031040);            //   524,288
  float*          X0    = (float*)(ws + 3555328);            // 4,194,304
  float*          hdec  = (float*)(ws + 7749632);            // 1,048,576
  unsigned short* Whh0b = (unsigned short*)(ws + 8798208);   // 8,388,608
  unsigned short* Wih1b = (unsigned short*)(ws + 17186816);  // 8,388,608
  unsigned short* Whh1b = (unsigned short*)(ws + 25575424);  // 8,388,608 -> 33,964,032
  float*          out   = (float*)d_out;

  k_cvt<<<6656, 256, 0, stream>>>(Whh0, Wih1, Whh1, Wout, Whh0b, Wih1b, Whh1b, Woutb);
  k_prep<<<64, 256, 0, stream>>>(ys, emb, eys, exch);
  // X0 = eys @ Wih0^T + bih0 + bhh0   (f32 out; M=256, N=4096, K=512)
  k_gemm_bias<<<256, 256, 0, stream>>>(eys, Wih0, bih0, bhh0, X0, 0, 256, 4096, 512);
  // encpb = bf16(hs @ Wenc^T + benc)  (M=512, N=512, K=512)
  k_gemm_bias<<<64, 256, 0, stream>>>(hs, Wenc, benc, nullptr, encpb, 1, 512, 512, 512);
  // fused LSTM v5: split-layer blocks, decoupled chains
  k_lstm_fused<<<128, 512, 0, stream>>>(X0, hdec, Whh0b, Wih1b, Whh1b, bih1, bhh1, exch);
  // decpb = bf16(hdec @ Wdec^T)       (M=256, N=512, K=1024)
  k_gemm_bias<<<32, 256, 0, stream>>>(hdec, Wdec, nullptr, nullptr, decpb, 1, 256, 512, 1024);
  // Z = tanh(enc + dec) materialized bf16
  k_z<<<8192, 256, 0, stream>>>(encpb, decpb, Z);
  // out = Z @ Wout^T + bout (64-col Wout slice LDS-resident; 512 blocks, 2/CU)
  k_gemm_out<<<512, 512, 0, stream>>>(Z, Woutb, bout, out);
}

// Round 17
// 419.489 us; speedup vs baseline: 3.0037x; 1.2753x over previous
//
#include <hip/hip_runtime.h>
#include <stdint.h>

typedef short bf16x8 __attribute__((ext_vector_type(8)));
typedef float f32x4 __attribute__((ext_vector_type(4)));
typedef unsigned int u32x4 __attribute__((ext_vector_type(4)));

__device__ __forceinline__ unsigned short f2bf(float f) {
  union { float f; unsigned int i; } v; v.f = f;
  unsigned int r = v.i + 0x7FFF + ((v.i >> 16) & 1);
  return (unsigned short)(r >> 16);
}
__device__ __forceinline__ float bfu2f(unsigned short u) {
  union { unsigned int i; float f; } v; v.i = ((unsigned int)u) << 16; return v.f;
}
__device__ __forceinline__ void gload_lds16(const void* g, void* l) {
  __builtin_amdgcn_global_load_lds(
      (const __attribute__((address_space(1))) unsigned int*)g,
      (__attribute__((address_space(3))) unsigned int*)l,
      16, 0, 0);
}
// coherent (IC-level) 16B store: single instruction => tag+data commit atomically
__device__ __forceinline__ void store16_coh(unsigned int* p, u32x4 v) {
  asm volatile("global_store_dwordx4 %0, %1, off sc0 sc1" :: "v"(p), "v"(v) : "memory");
}
__device__ __forceinline__ void spin_load6(const unsigned int* p0, const unsigned int* p1,
                                           const unsigned int* p2, const unsigned int* p3,
                                           const unsigned int* p4, const unsigned int* p5,
                                           u32x4& r0, u32x4& r1, u32x4& r2,
                                           u32x4& r3, u32x4& r4, u32x4& r5) {
  asm volatile(
      "global_load_dwordx4 %0, %6, off sc0 sc1\n\t"
      "global_load_dwordx4 %1, %7, off sc0 sc1\n\t"
      "global_load_dwordx4 %2, %8, off sc0 sc1\n\t"
      "global_load_dwordx4 %3, %9, off sc0 sc1\n\t"
      "global_load_dwordx4 %4, %10, off sc0 sc1\n\t"
      "global_load_dwordx4 %5, %11, off sc0 sc1\n\t"
      "s_waitcnt vmcnt(0)"
      : "=&v"(r0), "=&v"(r1), "=&v"(r2), "=&v"(r3), "=&v"(r4), "=&v"(r5)
      : "v"(p0), "v"(p1), "v"(p2), "v"(p3), "v"(p4), "v"(p5)
      : "memory");
}
// 3 record loads + 1 probe-tag load (L0 spin body)
__device__ __forceinline__ void spin_load3p(const unsigned int* p0, const unsigned int* p1,
                                            const unsigned int* p2, const unsigned int* pp,
                                            u32x4& r0, u32x4& r1, u32x4& r2, unsigned int& pt) {
  asm volatile(
      "global_load_dwordx4 %0, %4, off sc0 sc1\n\t"
      "global_load_dwordx4 %1, %5, off sc0 sc1\n\t"
      "global_load_dwordx4 %2, %6, off sc0 sc1\n\t"
      "global_load_dword %3, %7, off sc0 sc1\n\t"
      "s_waitcnt vmcnt(0)"
      : "=&v"(r0), "=&v"(r1), "=&v"(r2), "=&v"(pt)
      : "v"(p0), "v"(p1), "v"(p2), "v"(pp)
      : "memory");
}

// -------- merged cvt+prep: blocks 0..6655 convert weights; 6656..6719 do prep ---------
__global__ __launch_bounds__(256) void k_cvtprep(const float* __restrict__ s0, const float* __restrict__ s1,
                                                 const float* __restrict__ s2, const float* __restrict__ s3,
                                                 unsigned short* __restrict__ d0, unsigned short* __restrict__ d1,
                                                 unsigned short* __restrict__ d2, unsigned short* __restrict__ d3,
                                                 const int* __restrict__ ys,
                                                 const float* __restrict__ embed,
                                                 float* __restrict__ eys,
                                                 unsigned int* __restrict__ exch) {
  if (blockIdx.x < 6656) {
    int j = blockIdx.x * 256 + threadIdx.x;   // 1,703,936 vec8 jobs
    const float* s; unsigned short* d; int o;
    if (j < 524288)       { s = s0; d = d0; o = j; }
    else if (j < 1048576) { s = s1; d = d1; o = j - 524288; }
    else if (j < 1572864) { s = s2; d = d2; o = j - 1048576; }
    else                  { s = s3; d = d3; o = j - 1572864; }
    size_t off = (size_t)o * 8;
    f32x4 v0 = *(const f32x4*)(s + off);
    f32x4 v1 = *(const f32x4*)(s + off + 4);
    bf16x8 r;
#pragma unroll
    for (int k = 0; k < 4; k++) { r[k] = (short)f2bf(v0[k]); r[4 + k] = (short)f2bf(v1[k]); }
    *(bf16x8*)(d + off) = r;
  } else {
    int idx = (blockIdx.x - 6656) * 256 + threadIdx.x;   // 16384 threads
    int row = idx >> 6;
    int e = (idx & 63) * 8;
    int y = ys[row];
    f32x4 v0 = {0.f, 0.f, 0.f, 0.f}, v1 = {0.f, 0.f, 0.f, 0.f};
    if (y != 0) {
      v0 = *(const f32x4*)(embed + (size_t)y * 512 + e);
      v1 = *(const f32x4*)(embed + (size_t)y * 512 + e + 4);
    }
    *(f32x4*)(eys + (size_t)row * 512 + e) = v0;
    *(f32x4*)(eys + (size_t)row * 512 + e + 4) = v1;
    exch[idx] = 0u;                 // 32768 dwords: h0[2][8192] + h1[2][8192]
    exch[idx + 16384] = 0u;
  }
}

// -------- generic small GEMM: C = A(f32 MxK) @ W(f32 NxK)^T + b1 + b2; C f32 or bf16 ----
__global__ __launch_bounds__(256) void k_gemm_bias(const float* __restrict__ A,
                                                   const float* __restrict__ W,
                                                   const float* __restrict__ b1,
                                                   const float* __restrict__ b2,
                                                   void* __restrict__ Cout, int obf,
                                                   int M, int N, int K) {
  __shared__ unsigned short Als[64][40];
  __shared__ unsigned short Wls[64][40];
  int tid = threadIdx.x;
  int lane = tid & 63, wid = tid >> 6;
  int mtiles = M >> 6;
  int mt = blockIdx.x % mtiles, nt = blockIdx.x / mtiles;
  int srow = tid >> 2, sseg = tid & 3;
  f32x4 acc[4];
#pragma unroll
  for (int nf = 0; nf < 4; nf++) acc[nf] = (f32x4){0.f, 0.f, 0.f, 0.f};

  for (int kc = 0; kc < K; kc += 32) {
    const float* ap = A + (size_t)(mt * 64 + srow) * K + kc + sseg * 8;
    const float* wp = W + (size_t)(nt * 64 + srow) * K + kc + sseg * 8;
    f32x4 a0 = *(const f32x4*)ap, a1 = *(const f32x4*)(ap + 4);
    f32x4 w0 = *(const f32x4*)wp, w1 = *(const f32x4*)(wp + 4);
    bf16x8 av, wv;
#pragma unroll
    for (int k = 0; k < 4; k++) {
      av[k] = (short)f2bf(a0[k]); av[4 + k] = (short)f2bf(a1[k]);
      wv[k] = (short)f2bf(w0[k]); wv[4 + k] = (short)f2bf(w1[k]);
    }
    __syncthreads();
    *(bf16x8*)(&Als[srow][sseg * 8]) = av;
    *(bf16x8*)(&Wls[srow][sseg * 8]) = wv;
    __syncthreads();
    bf16x8 af = *(const bf16x8*)(&Als[wid * 16 + (lane & 15)][(lane >> 4) * 8]);
#pragma unroll
    for (int nf = 0; nf < 4; nf++) {
      bf16x8 bf = *(const bf16x8*)(&Wls[nf * 16 + (lane & 15)][(lane >> 4) * 8]);
      acc[nf] = __builtin_amdgcn_mfma_f32_16x16x32_bf16(af, bf, acc[nf], 0, 0, 0);
    }
  }
  int rloc = (lane >> 4) * 4;
  int col0 = lane & 15;
#pragma unroll
  for (int nf = 0; nf < 4; nf++) {
    int n = nt * 64 + nf * 16 + col0;
    float bias = 0.f;
    if (b1) bias += b1[n];
    if (b2) bias += b2[n];
#pragma unroll
    for (int r = 0; r < 4; r++) {
      int m = mt * 64 + wid * 16 + rloc + r;
      float v = acc[nf][r] + bias;
      if (obf) ((unsigned short*)Cout)[(size_t)m * N + n] = f2bf(v);
      else     ((float*)Cout)[(size_t)m * N + n] = v;
    }
  }
}

// ---------------- fused LSTM v5: split L0/L1 blocks, decoupled chains (r14 verbatim) ----
__global__ __launch_bounds__(512) void k_lstm_fused(
    const float* __restrict__ X0,            // (B,U,4096)
    float* __restrict__ hdec,                // (B,U,1024) f32
    const unsigned short* __restrict__ W_hh0,
    const unsigned short* __restrict__ W_ih1,
    const unsigned short* __restrict__ W_hh1,
    const float* __restrict__ b_ih1,
    const float* __restrict__ b_hh1,
    unsigned int* __restrict__ exch) {       // h0:[2][8192]dw, h1:+16384:[2][8192]dw
  __shared__ unsigned short X_lds[4][2064];
  __shared__ float red[8][4][16][4];
  int tid = threadIdx.x;
  int lane = tid & 63, w = tid >> 6;
  bool isL1 = blockIdx.x >= 64;
  int bidl = blockIdx.x & 63;
  int base = bidl * 16;
  unsigned int* REC0 = exch;
  unsigned int* REC1 = exch + 16384;

  bf16x8 wf[4][8];                           // L0 uses [.][0..3]
  int ch = lane & 15;
  int klo = (lane >> 4) << 3;
  int kb = isL1 ? w * 256 : w * 128;
#pragma unroll
  for (int nt = 0; nt < 4; nt++) {
    int grow = nt * 1024 + base + ch;
    if (!isL1) {
#pragma unroll
      for (int ks = 0; ks < 4; ks++)
        wf[nt][ks] = *(const bf16x8*)(W_hh0 + (size_t)grow * 1024 + kb + ks * 32 + klo);
    } else {
#pragma unroll
      for (int ks = 0; ks < 8; ks++) {
        int k = kb + ks * 32 + klo;
        const unsigned short* src = (k < 1024) ? (W_ih1 + (size_t)grow * 1024 + k)
                                               : (W_hh1 + (size_t)grow * 1024 + (k - 1024));
        wf[nt][ks] = *(const bf16x8*)src;
      }
    }
  }

  float creg = 0.f;
  float bs0 = 0.f, bs1 = 0.f, bs2 = 0.f, bs3 = 0.f;
  int gch = tid >> 2, gb = tid & 3;
  if (isL1 && tid < 64) {
    int c = base + gch;
    bs0 = b_ih1[c] + b_hh1[c];
    bs1 = b_ih1[1024 + c] + b_hh1[1024 + c];
    bs2 = b_ih1[2048 + c] + b_hh1[2048 + c];
    bs3 = b_ih1[3072 + c] + b_hh1[3072 + c];
  }

  int uoff[3], upb[3], us[3]; bool uneed[3];
#pragma unroll
  for (int r = 0; r < 3; r++) {
    int u = tid + r * 512;
    uneed[r] = (u < 1408);
    int uc = uneed[r] ? u : 1407;
    int pb = uc / 22;
    int s = uc - pb * 22;
    upb[r] = pb; us[r] = s;
    uoff[r] = pb * 128 + s * 4;
  }

#define STAGE_UNIT(rv, rr, off1024)                                           \
  if (uneed[rv]) {                                                            \
    int pb_ = upb[rv], s_ = us[rv];                                           \
    _Pragma("unroll")                                                         \
    for (int j_ = 0; j_ < 3; j_++) {                                          \
      int i_ = 3 * s_ + j_;                                                   \
      if (i_ < 64) {                                                          \
        union { unsigned int u; float f; } cv_; cv_.u = rr[j_];               \
        X_lds[i_ & 3][off1024 + pb_ * 16 + (i_ >> 2)] = f2bf(cv_.f);          \
      }                                                                       \
    }                                                                         \
  }

  int ar = ch & 3;
  if (!isL1) {
    for (int p = 0; p < 64; p++) {
      float xp0 = 0.f, xp1 = 0.f, xp2 = 0.f, xp3 = 0.f;
      if (tid < 64) {
        const float* x0p = X0 + ((size_t)(gb * 64 + p)) * 4096 + base + gch;
        xp0 = x0p[0]; xp1 = x0p[1024]; xp2 = x0p[2048]; xp3 = x0p[3072];
      }
      {
        unsigned int* b0 = REC0 + (unsigned)(p & 1) * 8192;
        const unsigned int* pp = REC1 + (unsigned)((p - 1) & 1) * 8192 + (tid & 63) * 128 + 3;
        unsigned expP = (p == 0) ? 0u : (unsigned)(p - 1);
        u32x4 r0, r1, r2; unsigned int pt;
        while (true) {
          spin_load3p(b0 + uoff[0], b0 + uoff[1], b0 + uoff[2], pp, r0, r1, r2, pt);
          bool ok = (!uneed[0] || r0[3] == (unsigned)p) && (!uneed[1] || r1[3] == (unsigned)p) &&
                    (!uneed[2] || r2[3] == (unsigned)p) && (pt >= expP);
          if (ok) break;
          __builtin_amdgcn_s_sleep(1);
        }
        STAGE_UNIT(0, r0, 0) STAGE_UNIT(1, r1, 0) STAGE_UNIT(2, r2, 0)
      }
      __syncthreads();
      {
        f32x4 acc[4];
#pragma unroll
        for (int nt = 0; nt < 4; nt++) acc[nt] = (f32x4){0.f, 0.f, 0.f, 0.f};
#pragma unroll
        for (int ks = 0; ks < 4; ks++) {
          bf16x8 a = *(const bf16x8*)&X_lds[ar][kb + ks * 32 + klo];
#pragma unroll
          for (int nt = 0; nt < 4; nt++)
            acc[nt] = __builtin_amdgcn_mfma_f32_16x16x32_bf16(a, wf[nt][ks], acc[nt], 0, 0, 0);
        }
        if (lane < 16) {
#pragma unroll
          for (int nt = 0; nt < 4; nt++) *(f32x4*)&red[w][nt][lane][0] = acc[nt];
        }
      }
      __syncthreads();
      if (tid < 64) {
        float g0 = 0.f, g1 = 0.f, g2 = 0.f, g3 = 0.f;
#pragma unroll
        for (int w8 = 0; w8 < 8; w8++) {
          g0 += red[w8][0][gch][gb]; g1 += red[w8][1][gch][gb];
          g2 += red[w8][2][gch][gb]; g3 += red[w8][3][gch][gb];
        }
        g0 += xp0; g1 += xp1; g2 += xp2; g3 += xp3;
        float ii = 1.f / (1.f + __expf(-g0));
        float ff = 1.f / (1.f + __expf(-g1));
        float oo = 1.f / (1.f + __expf(-g3));
        float cn = ff * creg + ii * tanhf(g2);
        creg = cn;
        float hn = oo * tanhf(cn);
        int l = tid;
        float v0 = __shfl(hn, 3 * l);
        float v1 = __shfl(hn, 3 * l + 1);
        float v2 = __shfl(hn, 3 * l + 2);
        if (l < 22) {
          unsigned tag = (unsigned)(p + 1);
          unsigned int* rec = REC0 + (tag & 1) * 8192 + bidl * 128 + l * 4;
          u32x4 d;
          d[0] = __float_as_uint(v0); d[1] = __float_as_uint(v1);
          d[2] = __float_as_uint(v2); d[3] = tag;
          store16_coh(rec, d);
        }
      }
    }
  } else {
    for (int p = 1; p <= 64; p++) {
      {
        unsigned int* b0 = REC0 + (unsigned)(p & 1) * 8192;
        unsigned int* b1 = REC1 + (unsigned)((p - 1) & 1) * 8192;
        u32x4 r0, r1, r2, r3, r4, r5;
        unsigned exp0 = (unsigned)p, exp1 = (unsigned)(p - 1);
        while (true) {
          spin_load6(b0 + uoff[0], b0 + uoff[1], b0 + uoff[2],
                     b1 + uoff[0], b1 + uoff[1], b1 + uoff[2],
                     r0, r1, r2, r3, r4, r5);
          bool ok = (!uneed[0] || (r0[3] == exp0 && r3[3] == exp1)) &&
                    (!uneed[1] || (r1[3] == exp0 && r4[3] == exp1)) &&
                    (!uneed[2] || (r2[3] == exp0 && r5[3] == exp1));
          if (ok) break;
          __builtin_amdgcn_s_sleep(1);
        }
        STAGE_UNIT(0, r0, 0) STAGE_UNIT(1, r1, 0) STAGE_UNIT(2, r2, 0)
        STAGE_UNIT(0, r3, 1024) STAGE_UNIT(1, r4, 1024) STAGE_UNIT(2, r5, 1024)
      }
      __syncthreads();
      {
        f32x4 acc[4];
#pragma unroll
        for (int nt = 0; nt < 4; nt++) acc[nt] = (f32x4){0.f, 0.f, 0.f, 0.f};
#pragma unroll
        for (int ks = 0; ks < 8; ks++) {
          bf16x8 a = *(const bf16x8*)&X_lds[ar][kb + ks * 32 + klo];
#pragma unroll
          for (int nt = 0; nt < 4; nt++)
            acc[nt] = __builtin_amdgcn_mfma_f32_16x16x32_bf16(a, wf[nt][ks], acc[nt], 0, 0, 0);
        }
        if (lane < 16) {
#pragma unroll
          for (int nt = 0; nt < 4; nt++) *(f32x4*)&red[w][nt][lane][0] = acc[nt];
        }
      }
      __syncthreads();
      if (tid < 64) {
        float g0 = 0.f, g1 = 0.f, g2 = 0.f, g3 = 0.f;
#pragma unroll
        for (int w8 = 0; w8 < 8; w8++) {
          g0 += red[w8][0][gch][gb]; g1 += red[w8][1][gch][gb];
          g2 += red[w8][2][gch][gb]; g3 += red[w8][3][gch][gb];
        }
        g0 += bs0; g1 += bs1; g2 += bs2; g3 += bs3;
        float ii = 1.f / (1.f + __expf(-g0));
        float ff = 1.f / (1.f + __expf(-g1));
        float oo = 1.f / (1.f + __expf(-g3));
        float cn = ff * creg + ii * tanhf(g2);
        creg = cn;
        float hn = oo * tanhf(cn);
        hdec[((size_t)(gb * 64 + (p - 1))) * 1024 + base + gch] = hn;
        int l = tid;
        float v0 = __shfl(hn, 3 * l);
        float v1 = __shfl(hn, 3 * l + 1);
        float v2 = __shfl(hn, 3 * l + 2);
        if (l < 22) {
          unsigned tag = (unsigned)p;
          unsigned int* rec = REC1 + (tag & 1) * 8192 + bidl * 128 + l * 4;
          u32x4 d;
          d[0] = __float_as_uint(v0); d[1] = __float_as_uint(v1);
          d[2] = __float_as_uint(v2); d[3] = tag;
          store16_coh(rec, d);
        }
      }
    }
  }
#undef STAGE_UNIT
}

// ---------------- k_z: Z[m][k] = tanh(encp[b,t,k] + decp[b,u,k]) as bf16 --------------
__global__ __launch_bounds__(256) void k_z(const unsigned short* __restrict__ encpb, // (512,512) bf16
                                           const unsigned short* __restrict__ decpb, // (256,512) bf16
                                           unsigned short* __restrict__ Z) {
  int idx = blockIdx.x * 256 + threadIdx.x;   // 2,097,152 jobs (8192 blocks)
  int m = idx >> 6;
  int k0 = (idx & 63) * 8;
  int bt = m >> 6;                            // b*128+t
  int b = m >> 13, u = m & 63;
  bf16x8 ev = *(const bf16x8*)(encpb + (size_t)bt * 512 + k0);
  bf16x8 dv = *(const bf16x8*)(decpb + (size_t)(b * 64 + u) * 512 + k0);
  bf16x8 r;
#pragma unroll
  for (int j = 0; j < 8; j++) {
    float x = bfu2f((unsigned short)ev[j]) + bfu2f((unsigned short)dv[j]);
    float e = __expf(x + x);
    r[j] = (short)f2bf(1.f - 2.f / (e + 1.f));
  }
  *(bf16x8*)(Z + (size_t)m * 512 + k0) = r;
}

// ------- k_gemm_out (r14-verified): 256 blocks (16 m-parts x 16 n-groups of 128) -------
// Block stages its 128-col Wout slice (128KB) once into LDS; streams 2048 contiguous rows.
__global__ __launch_bounds__(512, 2) void k_gemm_out(const unsigned short* __restrict__ Z,    // (32768,512) bf16
                                                     const unsigned short* __restrict__ Wout, // (2048,512) bf16
                                                     const float* __restrict__ bout,          // (2048) f32
                                                     float* __restrict__ out) {               // (32768,2048) f32
  __shared__ unsigned short Wls[8][8192];   // 8 k-chunks x (128 n-rows x 64 k, swizzled)
  int tid = threadIdx.x;
  int lane = tid & 63, wid = tid >> 6;
  int bid = blockIdx.x;
  int mpart = bid & 15, ngroup = bid >> 4;

#pragma unroll
  for (int kc = 0; kc < 8; kc++) {
    unsigned short* dst = &Wls[kc][0];
#pragma unroll
    for (int q = 0; q < 2; q++) {
      int idx = tid + q * 512;
      int n = idx >> 3, sl = idx & 7;
      int ss = sl ^ (n & 7);
      gload_lds16(Wout + (size_t)(ngroup * 128 + n) * 512 + kc * 64 + ss * 8, dst + idx * 8);
    }
  }
  float bb[8];
#pragma unroll
  for (int nf = 0; nf < 8; nf++) bb[nf] = bout[ngroup * 128 + nf * 16 + (lane & 15)];
  asm volatile("s_waitcnt vmcnt(0)" ::: "memory");
  __syncthreads();

  int rowwave = mpart * 2048 + wid * 256;
  int ocol0 = ngroup * 128;
  for (int mg = 0; mg < 4; mg++) {
    int rowbase = rowwave + mg * 64;
    f32x4 acc[4][8];
#pragma unroll
    for (int mf = 0; mf < 4; mf++)
#pragma unroll
      for (int nf = 0; nf < 8; nf++) acc[mf][nf] = (f32x4){0.f, 0.f, 0.f, 0.f};

#pragma unroll
    for (int ks = 0; ks < 16; ks++) {
      bf16x8 a[4];
#pragma unroll
      for (int mf = 0; mf < 4; mf++) {
        int r = rowbase + mf * 16 + (lane & 15);
        a[mf] = *(const bf16x8*)(Z + (size_t)r * 512 + ks * 32 + ((lane >> 4) << 3));
      }
      const unsigned short* Wb = &Wls[ks >> 1][0];
      int slot = (ks & 1) * 4 + (lane >> 4);
#pragma unroll
      for (int nf = 0; nf < 8; nf++) {
        int nl = nf * 16 + (lane & 15);
        int phys = slot ^ (nl & 7);
        bf16x8 bfr = *(const bf16x8*)(Wb + nl * 64 + phys * 8);
#pragma unroll
        for (int mf = 0; mf < 4; mf++)
          acc[mf][nf] = __builtin_amdgcn_mfma_f32_16x16x32_bf16(a[mf], bfr, acc[mf][nf], 0, 0, 0);
      }
    }
#pragma unroll
    for (int mf = 0; mf < 4; mf++) {
      int rb = rowbase + mf * 16 + ((lane >> 4) << 2);
#pragma unroll
      for (int nf = 0; nf < 8; nf++) {
        int o = ocol0 + nf * 16 + (lane & 15);
        float bias = bb[nf];
#pragma unroll
        for (int q = 0; q < 4; q++)
          __builtin_nontemporal_store(acc[mf][nf][q] + bias, &out[(size_t)(rb + q) * 2048 + o]);
      }
    }
  }
}

// ---------------- launch ----------------
extern "C" void kernel_launch(void* const* d_in, const int* in_sizes, int n_in,
                              void* d_out, int out_size, void* d_ws, size_t ws_size,
                              hipStream_t stream) {
  const float* hs   = (const float*)d_in[0];
  const int*   ys   = (const int*)d_in[1];
  const float* emb  = (const float*)d_in[2];
  const float* Wih0 = (const float*)d_in[3];
  const float* Whh0 = (const float*)d_in[4];
  const float* bih0 = (const float*)d_in[5];
  const float* bhh0 = (const float*)d_in[6];
  const float* Wih1 = (const float*)d_in[7];
  const float* Whh1 = (const float*)d_in[8];
  const float* bih1 = (const float*)d_in[9];
  const float* bhh1 = (const float*)d_in[10];
  const float* Wenc = (const float*)d_in[11];
  const float* benc = (const float*)d_in[12];
  const float* Wdec = (const float*)d_in[13];
  const float* Wout = (const float*)d_in[14];
  const float* bout = (const float*)d_in[15];

  // Workspace map (liveness-overlapped, r14-identical):
  char* ws = (char*)d_ws;
  unsigned short* Woutb = (unsigned short*)(ws + 0);
  unsigned short* encpb = (unsigned short*)(ws + 2097152);
  unsigned short* decpb = (unsigned short*)(ws + 2621440);
  unsigned int*   exch  = (unsigned int*)(ws + 2883584);
  unsigned short* Z     = (unsigned short*)(ws + 3031040);
  float*          eys   = (float*)(ws + 3031040);            //   524,288
  float*          X0    = (float*)(ws + 3555328);            // 4,194,304
  float*          hdec  = (float*)(ws + 7749632);            // 1,048,576
  unsigned short* Whh0b = (unsigned short*)(ws + 8798208);   // 8,388,608
  unsigned short* Wih1b = (unsigned short*)(ws + 17186816);  // 8,388,608
  unsigned short* Whh1b = (unsigned short*)(ws + 25575424);  // 8,388,608 -> 33,964,032
  float*          out   = (float*)d_out;

  // merged weight conversion + prep (independent work, one launch)
  k_cvtprep<<<6720, 256, 0, stream>>>(Whh0, Wih1, Whh1, Wout, Whh0b, Wih1b, Whh1b, Woutb,
                                      ys, emb, eys, exch);
  // X0 = eys @ Wih0^T + bih0 + bhh0   (f32 out; M=256, N=4096, K=512)
  k_gemm_bias<<<256, 256, 0, stream>>>(eys, Wih0, bih0, bhh0, X0, 0, 256, 4096, 512);
  // encpb = bf16(hs @ Wenc^T + benc)  (M=512, N=512, K=512)
  k_gemm_bias<<<64, 256, 0, stream>>>(hs, Wenc, benc, nullptr, encpb, 1, 512, 512, 512);
  // fused LSTM v5: split-layer blocks, decoupled chains
  k_lstm_fused<<<128, 512, 0, stream>>>(X0, hdec, Whh0b, Wih1b, Whh1b, bih1, bhh1, exch);
  // decpb = bf16(hdec @ Wdec^T)       (M=256, N=512, K=1024)
  k_gemm_bias<<<32, 256, 0, stream>>>(hdec, Wdec, nullptr, nullptr, decpb, 1, 256, 512, 1024);
  // Z = tanh(enc + dec) materialized bf16
  k_z<<<8192, 256, 0, stream>>>(encpb, decpb, Z);
  // out = Z @ Wout^T + bout (128-col Wout slice LDS-resident; 256 blocks)
  k_gemm_out<<<256, 512, 0, stream>>>(Z, Woutb, bout, out);
}